// Round 6
// baseline (378.237 us; speedup 1.0000x reference)
//
#include <hip/hip_runtime.h>

// LaterallyConnectedLayer: B=16, NUM_FM=64, N=4, NF=256, H=W=32, KS=5. All fp32.
// Derived math:
//   w1t[i][o][k]  = minmax5x5( K[i][o] )                (i-major layout)
//   wsum2[g][o][k]= sum_n w1t[64n+g][o][k]
//   score[b,o]    = (sum-1024*min)/(max-min) over conv_same(A[b,:],wsum[o,:])*S[o]
//   n*[b,f]       = argmax_n score[b,64n+f]  (first-max ties; const A-term drops)
//   out[b,f]      = (1/64) sum_g conv_same(A[b,g], w1[64n*_f+f][64n*_g+g])

#define NFM 64
#define NMX 4
#define NFC 256
#define HW 1024
#define KK 25

// --- kprep: normalize K -> w1t (coalesced), accumulate wsum2 ----------------
__global__ __launch_bounds__(256) void kprep(const float* __restrict__ K,
                                             float* __restrict__ w1t,
                                             float* __restrict__ wsum2) {
    __shared__ __align__(16) float buf[64 * KK];
    int g = blockIdx.x & 63, o0 = (blockIdx.x >> 6) * 64;
    int t = threadIdx.x;
    float wacc[KK];
#pragma unroll
    for (int k = 0; k < KK; ++k) wacc[k] = 0.f;

    for (int n = 0; n < NMX; ++n) {
        int i = n * NFM + g;
        const float4* src = (const float4*)(K + (i * NFC + o0) * KK);
        __syncthreads();
        ((float4*)buf)[t] = src[t];
        if (t < 144) ((float4*)buf)[t + 256] = src[t + 256];
        __syncthreads();
        if (t < 64) {
            float v[KK];
            float mn = 1e30f, mx = -1e30f;
#pragma unroll
            for (int k = 0; k < KK; ++k) {
                v[k] = buf[t * KK + k];
                mn = fminf(mn, v[k]);
                mx = fmaxf(mx, v[k]);
            }
            float d = mx - mn;
            float r = d > 0.f ? 1.f / d : 0.f;
#pragma unroll
            for (int k = 0; k < KK; ++k) {
                float nv = (v[k] - mn) * r;
                buf[t * KK + k] = nv;
                wacc[k] += nv;
            }
        }
        __syncthreads();
        float4* dst = (float4*)(w1t + (i * NFC + o0) * KK);
        dst[t] = ((float4*)buf)[t];
        if (t < 144) dst[t + 256] = ((float4*)buf)[t + 256];
    }
    __syncthreads();
    if (t < 64) {
#pragma unroll
        for (int k = 0; k < KK; ++k) buf[t * KK + k] = wacc[k];
    }
    __syncthreads();
    float4* dst = (float4*)(wsum2 + (g * NFC + o0) * KK);
    dst[t] = ((float4*)buf)[t];
    if (t < 144) dst[t + 256] = ((float4*)buf)[t + 256];
}

// --- kscore: grid (32,2,16). Wave = o-pair x HALF image, wave-private LDS ---
// Writes per-(b,o,half) partial stats (min,max,sum) as float4 to part[].
__global__ __launch_bounds__(256) void kscore(const float* __restrict__ A,
                                              const float* __restrict__ wsum2,
                                              const float* __restrict__ S,
                                              float4* __restrict__ part) {
    __shared__ __align__(16) float pa[4][20 * 36 + 4];
    int t = threadIdx.x, z = blockIdx.y, b = blockIdx.z;
    int wv = __builtin_amdgcn_readfirstlane(t >> 6);
    int lane = t & 63;
    int ob = blockIdx.x * 8 + wv * 2;
    int y0 = z * 16;
    int xb = (lane & 7) * 4;
    int yb = (lane >> 3) * 2;            // 0..14
    float* buf = pa[wv];

    for (int i = lane; i < 20 * 36; i += 64) buf[i] = 0.f;
    __builtin_amdgcn_wave_barrier();

    const float* Ab = A + b * NFM * HW;
    // staging: 160 f4 slots (20 rows x 8); lane handles s = lane, +64, +128(<32)
    int s0 = lane, s1 = lane + 64, s2 = lane + 128;
    int r0 = s0 >> 3, r1 = s1 >> 3, r2 = s2 >> 3;
    int gy0 = y0 - 2 + r0, gy1 = y0 - 2 + r1, gy2 = y0 - 2 + r2;
    int c0 = (s0 & 7) * 4, c1 = (s1 & 7) * 4, c2 = (s2 & 7) * 4;
    bool v0 = (gy0 >= 0) && (gy0 < 32);
    bool v1 = (gy1 >= 0) && (gy1 < 32);
    bool v2 = (lane < 32) && (gy2 >= 0) && (gy2 < 32);
    float* d0 = &buf[r0 * 36 + c0 + 2];
    float* d1 = &buf[r1 * 36 + c1 + 2];
    float* d2 = &buf[r2 * 36 + c2 + 2];

    {   // stage g = 0
        if (v0) { float4 q = *(const float4*)(Ab + gy0 * 32 + c0);
                  *(float2*)&d0[0] = make_float2(q.x, q.y);
                  *(float2*)&d0[2] = make_float2(q.z, q.w); }
        if (v1) { float4 q = *(const float4*)(Ab + gy1 * 32 + c1);
                  *(float2*)&d1[0] = make_float2(q.x, q.y);
                  *(float2*)&d1[2] = make_float2(q.z, q.w); }
        if (v2) { float4 q = *(const float4*)(Ab + gy2 * 32 + c2);
                  *(float2*)&d2[0] = make_float2(q.x, q.y);
                  *(float2*)&d2[2] = make_float2(q.z, q.w); }
    }
    __builtin_amdgcn_wave_barrier();

    float acc0[8], acc1[8];
#pragma unroll
    for (int j = 0; j < 8; ++j) { acc0[j] = 0.f; acc1[j] = 0.f; }

    for (int g = 0; g < NFM; ++g) {
        float4 q0, q1, q2;
        bool more = (g + 1) < NFM;
        if (more) {
            const float* Ag = Ab + (g + 1) * HW;
            if (v0) q0 = *(const float4*)(Ag + gy0 * 32 + c0);
            if (v1) q1 = *(const float4*)(Ag + gy1 * 32 + c1);
            if (v2) q2 = *(const float4*)(Ag + gy2 * 32 + c2);
        }

        const float* wg = wsum2 + (g * NFC + ob) * KK;   // uniform -> s_load
        float w0[KK], w1r[KK];
#pragma unroll
        for (int k = 0; k < KK; ++k) { w0[k] = wg[k]; w1r[k] = wg[KK + k]; }

#pragma unroll
        for (int r = 0; r < 6; ++r) {
            float4 a0 = *(const float4*)&buf[(yb + r) * 36 + xb];
            float4 a1 = *(const float4*)&buf[(yb + r) * 36 + xb + 4];
            float a[8] = {a0.x, a0.y, a0.z, a0.w, a1.x, a1.y, a1.z, a1.w};
#pragma unroll
            for (int py = 0; py < 2; ++py) {
                int u = r - py;
                if (u >= 0 && u < 5) {
#pragma unroll
                    for (int v = 0; v < 5; ++v) {
                        float wa = w0[u * 5 + v], wb = w1r[u * 5 + v];
#pragma unroll
                        for (int px = 0; px < 4; ++px) {
                            acc0[py * 4 + px] = fmaf(a[px + v], wa, acc0[py * 4 + px]);
                            acc1[py * 4 + px] = fmaf(a[px + v], wb, acc1[py * 4 + px]);
                        }
                    }
                }
            }
        }
        __builtin_amdgcn_wave_barrier();
        if (more) {
            if (v0) { *(float2*)&d0[0] = make_float2(q0.x, q0.y);
                      *(float2*)&d0[2] = make_float2(q0.z, q0.w); }
            if (v1) { *(float2*)&d1[0] = make_float2(q1.x, q1.y);
                      *(float2*)&d1[2] = make_float2(q1.z, q1.w); }
            if (v2) { *(float2*)&d2[0] = make_float2(q2.x, q2.y);
                      *(float2*)&d2[2] = make_float2(q2.z, q2.w); }
        }
        __builtin_amdgcn_wave_barrier();
    }

#pragma unroll
    for (int oo = 0; oo < 2; ++oo) {
        const float* ac = oo ? acc1 : acc0;
        float scale = S[ob + oo] * (1.f / 64.f);
        float lmn = 1e30f, lmx = -1e30f, lsum = 0.f;
#pragma unroll
        for (int j = 0; j < 8; ++j) {
            float vv = ac[j] * scale;
            lmn = fminf(lmn, vv);
            lmx = fmaxf(lmx, vv);
            lsum += vv;
        }
#pragma unroll
        for (int m = 1; m < 64; m <<= 1) {
            lmn = fminf(lmn, __shfl_xor(lmn, m, 64));
            lmx = fmaxf(lmx, __shfl_xor(lmx, m, 64));
            lsum += __shfl_xor(lsum, m, 64);
        }
        if (lane == 0)
            part[(b * NFC + ob + oo) * 2 + z] = make_float4(lmn, lmx, lsum, 0.f);
    }
}

// --- kfin: combine halves -> score -> argmax -> ig[b*64+f] ------------------
__global__ __launch_bounds__(256) void kfin(const float4* __restrict__ part,
                                            int* __restrict__ ig) {
    __shared__ float scl[NFC];
    int b = blockIdx.x, t = threadIdx.x;
    float4 p0 = part[(b * NFC + t) * 2 + 0];
    float4 p1 = part[(b * NFC + t) * 2 + 1];
    float mn = fminf(p0.x, p1.x);
    float mx = fmaxf(p0.y, p1.y);
    float sm = p0.z + p1.z;
    float d = mx - mn;
    scl[t] = d > 0.f ? (sm - 1024.f * mn) / d : 0.f;
    __syncthreads();
    if (t < NFM) {
        float best = scl[t];
        int bi = 0;
#pragma unroll
        for (int n = 1; n < NMX; ++n) {
            float v = scl[n * NFM + t];
            if (v > best) { best = v; bi = n; }   // first-max ties
        }
        ig[b * NFM + t] = bi * NFM + t;
    }
}

// --- kout: grid (8,4,16). Wave = f-pair x QUARTER image, wave-private LDS ---
__global__ __launch_bounds__(256) void kout(const float* __restrict__ A,
                                            const float* __restrict__ w1t,
                                            const int* __restrict__ ig,
                                            float* __restrict__ out) {
    __shared__ __align__(16) float pa[4][12 * 36 + 4];
    int t = threadIdx.x, q = blockIdx.y, b = blockIdx.z;
    int wv = __builtin_amdgcn_readfirstlane(t >> 6);
    int lane = t & 63;
    int f0 = blockIdx.x * 8 + wv * 2, f1 = f0 + 1;
    const int* igR = ig + b * NFM;                   // uniform row
    int o0 = igR[f0], o1 = igR[f1];                  // scalar loads
    int y0 = q * 8;
    int xb = (lane & 7) * 4;
    int yb = lane >> 3;                              // 0..7
    float* buf = pa[wv];

    for (int i = lane; i < 12 * 36; i += 64) buf[i] = 0.f;
    __builtin_amdgcn_wave_barrier();

    const float* Ab = A + b * NFM * HW;
    // staging: 96 f4 slots (12 rows x 8); lane handles s = lane, +64 (lane<32)
    int s0 = lane, s1 = lane + 64;
    int r0 = s0 >> 3, r1 = s1 >> 3;
    int gy0 = y0 - 2 + r0, gy1 = y0 - 2 + r1;
    int c0 = (s0 & 7) * 4, c1 = (s1 & 7) * 4;
    bool v0 = (gy0 >= 0) && (gy0 < 32);
    bool v1 = (lane < 32) && (gy1 >= 0) && (gy1 < 32);
    float* d0 = &buf[r0 * 36 + c0 + 2];
    float* d1 = &buf[r1 * 36 + c1 + 2];

    {
        if (v0) { float4 qq = *(const float4*)(Ab + gy0 * 32 + c0);
                  *(float2*)&d0[0] = make_float2(qq.x, qq.y);
                  *(float2*)&d0[2] = make_float2(qq.z, qq.w); }
        if (v1) { float4 qq = *(const float4*)(Ab + gy1 * 32 + c1);
                  *(float2*)&d1[0] = make_float2(qq.x, qq.y);
                  *(float2*)&d1[2] = make_float2(qq.z, qq.w); }
    }
    __builtin_amdgcn_wave_barrier();

    float acc0[4], acc1[4];
#pragma unroll
    for (int j = 0; j < 4; ++j) { acc0[j] = 0.f; acc1[j] = 0.f; }

    // weight register pipeline: wn holds g's weights entering iteration g
    float wn0[KK], wn1[KK];
    {
        int i0 = igR[0];
        const float* wp0 = w1t + (i0 * NFC + o0) * KK;
        const float* wp1 = w1t + (i0 * NFC + o1) * KK;
#pragma unroll
        for (int k = 0; k < KK; ++k) { wn0[k] = wp0[k]; wn1[k] = wp1[k]; }
    }

    for (int g = 0; g < NFM; ++g) {
        float4 q0, q1;
        bool more = (g + 1) < NFM;
        if (more) {
            const float* Ag = Ab + (g + 1) * HW;
            if (v0) q0 = *(const float4*)(Ag + gy0 * 32 + c0);
            if (v1) q1 = *(const float4*)(Ag + gy1 * 32 + c1);
        }

        float wc0[KK], wc1[KK];
#pragma unroll
        for (int k = 0; k < KK; ++k) { wc0[k] = wn0[k]; wc1[k] = wn1[k]; }
        if (more) {
            int ign = igR[g + 1];
            const float* wp0 = w1t + (ign * NFC + o0) * KK;
            const float* wp1 = w1t + (ign * NFC + o1) * KK;
#pragma unroll
            for (int k = 0; k < KK; ++k) { wn0[k] = wp0[k]; wn1[k] = wp1[k]; }
        }

#pragma unroll
        for (int u = 0; u < 5; ++u) {
            float4 a0 = *(const float4*)&buf[(yb + u) * 36 + xb];
            float4 a1 = *(const float4*)&buf[(yb + u) * 36 + xb + 4];
            float a[8] = {a0.x, a0.y, a0.z, a0.w, a1.x, a1.y, a1.z, a1.w};
#pragma unroll
            for (int v = 0; v < 5; ++v) {
                float wa = wc0[u * 5 + v], wb = wc1[u * 5 + v];
#pragma unroll
                for (int px = 0; px < 4; ++px) {
                    acc0[px] = fmaf(a[px + v], wa, acc0[px]);
                    acc1[px] = fmaf(a[px + v], wb, acc1[px]);
                }
            }
        }
        __builtin_amdgcn_wave_barrier();
        if (more) {
            if (v0) { *(float2*)&d0[0] = make_float2(q0.x, q0.y);
                      *(float2*)&d0[2] = make_float2(q0.z, q0.w); }
            if (v1) { *(float2*)&d1[0] = make_float2(q1.x, q1.y);
                      *(float2*)&d1[2] = make_float2(q1.z, q1.w); }
        }
        __builtin_amdgcn_wave_barrier();
    }

    {
        float4 qa, qb;
        qa.x = acc0[0] * (1.f / 64.f); qa.y = acc0[1] * (1.f / 64.f);
        qa.z = acc0[2] * (1.f / 64.f); qa.w = acc0[3] * (1.f / 64.f);
        qb.x = acc1[0] * (1.f / 64.f); qb.y = acc1[1] * (1.f / 64.f);
        qb.z = acc1[2] * (1.f / 64.f); qb.w = acc1[3] * (1.f / 64.f);
        *(float4*)&out[(b * NFM + f0) * HW + (y0 + yb) * 32 + xb] = qa;
        *(float4*)&out[(b * NFM + f1) * HW + (y0 + yb) * 32 + xb] = qb;
    }
}

extern "C" void kernel_launch(void* const* d_in, const int* in_sizes, int n_in,
                              void* d_out, int out_size, void* d_ws, size_t ws_size,
                              hipStream_t stream) {
    const float* A = (const float*)d_in[0];   // (16,64,32,32) f32
    const float* K = (const float*)d_in[1];   // (256,256,5,5) f32
    const float* S = (const float*)d_in[2];   // (256,) f32
    float* out = (float*)d_out;               // (16,64,32,32) f32

    char* ws = (char*)d_ws;
    float*  w1t   = (float*)ws;                        // 6,553,600 B
    float*  wsum2 = (float*)(ws + 6553600);            // 1,638,400 B
    float4* part  = (float4*)(ws + 8192000);           // 16*256*2*16 = 131,072 B
    int*    ig    = (int*)  (ws + 8323072);            // 4,096 B

    kprep<<<dim3(256), dim3(256), 0, stream>>>(K, w1t, wsum2);
    kscore<<<dim3(32, 2, 16), dim3(256), 0, stream>>>(A, wsum2, S, part);
    kfin<<<dim3(16), dim3(256), 0, stream>>>(part, ig);
    kout<<<dim3(8, 4, 16), dim3(256), 0, stream>>>(A, w1t, ig, out);
}

// Round 7
// 215.640 us; speedup vs baseline: 1.7540x; 1.7540x over previous
//
#include <hip/hip_runtime.h>

// LaterallyConnectedLayer: B=16, NUM_FM=64, N=4, NF=256, H=W=32, KS=5. fp32 I/O.
//   w1[i][o][k]   = minmax5x5( K[i][o] )
//   wsum[o][g][k] = sum_n w1[64n+g][o][k]
//   score[b,o]    = (sum-1024*min)/(max-min) over conv_same(A[b,:],wsum[o,:])*S[o]
//   n*[b,f]       = argmax_n score[b,64n+f]
//   out[b,f]      = (1/64) sum_g conv_same(A[b,g], w1[ig_g][ig_f]), ig_x = 64n*_x + x
// kscore is an implicit GEMM (M=256 o, N=1024 px x 16 b, K=1600=25dydx*64g) on MFMA
// 16x16x32 bf16 with hi/lo fp32 split (3 terms). Verified layouts (learn_hip m89):
//   A[m=lane&15][k=(lane>>4)*8+j], B[k=(lane>>4)*8+j][n=lane&15],
//   C col=lane&15, row=(lane>>4)*4+reg.

#define NFM 64
#define NMX 4
#define NFC 256
#define HW 1024
#define KK 25

typedef unsigned short u16;
typedef short short8 __attribute__((ext_vector_type(8)));
typedef short short4v __attribute__((ext_vector_type(4)));
typedef float f32x4 __attribute__((ext_vector_type(4)));

__device__ __forceinline__ u16 f2bfbits(float f) {
    unsigned int u = __float_as_uint(f);
    u += 0x7fffu + ((u >> 16) & 1u);   // RNE
    return (u16)(u >> 16);
}
__device__ __forceinline__ float bf2f(u16 v) {
    return __uint_as_float(((unsigned int)v) << 16);
}

// --- kprep: K -> w1h (bf16, [i][o][25]) + wsum2 (f32, [g][o][25]) -----------
// grid 256 = (g 0..63) x (o-quarter 0..3), 256 threads.
__global__ __launch_bounds__(256) void kprep(const float* __restrict__ K,
                                             u16* __restrict__ w1h,
                                             float* __restrict__ wsum2) {
    __shared__ __align__(16) float buf[64 * KK];    // 6400 B
    __shared__ __align__(16) u16 wbuf[64 * KK];     // 3200 B
    int g = blockIdx.x & 63, o0 = (blockIdx.x >> 6) * 64;
    int t = threadIdx.x;
    float wacc[KK];
#pragma unroll
    for (int k = 0; k < KK; ++k) wacc[k] = 0.f;

    for (int n = 0; n < NMX; ++n) {
        int i = n * NFM + g;
        const float4* src = (const float4*)(K + (i * NFC + o0) * KK);  // 400 f4
        __syncthreads();
        ((float4*)buf)[t] = src[t];
        if (t < 144) ((float4*)buf)[t + 256] = src[t + 256];
        __syncthreads();
        if (t < 64) {
            float v[KK];
            float mn = 1e30f, mx = -1e30f;
#pragma unroll
            for (int k = 0; k < KK; ++k) {
                v[k] = buf[t * KK + k];
                mn = fminf(mn, v[k]);
                mx = fmaxf(mx, v[k]);
            }
            float d = mx - mn;
            float r = d > 0.f ? 1.f / d : 0.f;
#pragma unroll
            for (int k = 0; k < KK; ++k) {
                float nv = (v[k] - mn) * r;
                wbuf[t * KK + k] = f2bfbits(nv);
                wacc[k] += nv;
            }
        }
        __syncthreads();
        // coalesced copy of 1600 u16 (3200 B = 200 x 16 B)
        uint4* dst = (uint4*)(w1h + (i * NFC + o0) * KK);
        if (t < 200) dst[t] = ((uint4*)wbuf)[t];
    }
    __syncthreads();
    if (t < 64) {
#pragma unroll
        for (int k = 0; k < KK; ++k) buf[t * KK + k] = wacc[k];
    }
    __syncthreads();
    float4* dst = (float4*)(wsum2 + (g * NFC + o0) * KK);
    dst[t] = ((float4*)buf)[t];
    if (t < 144) dst[t + 256] = ((float4*)buf)[t + 256];
}

// --- kpackW: wsum2 -> Wpk, MFMA A-fragment order, hi/lo chunk pairs ---------
// chunk c = (mt_global*50 + ks)*2 + h ; 1024 B each; lane l=(quad*16+(o&15)),
// 8 bf16 k-contiguous per lane. 51200 threads: (o, ks, quad).
__global__ __launch_bounds__(256) void kpackW(const float* __restrict__ wsum2,
                                              char* __restrict__ Wpk) {
    int id = blockIdx.x * 256 + threadIdx.x;     // < 51200
    int o = id / 200;
    int rem = id - o * 200;
    int ks = rem >> 2, quad = rem & 3;
    int dydx = ks >> 1;
    int gb = (ks & 1) * 32 + quad * 8;
    short8 hs, ls;
#pragma unroll
    for (int j = 0; j < 8; ++j) {
        float v = wsum2[((gb + j) * NFC + o) * KK + dydx];
        u16 h = f2bfbits(v);
        float lo = v - bf2f(h);
        hs[j] = (short)h;
        ls[j] = (short)f2bfbits(lo);
    }
    char* base = Wpk + (((o >> 4) * 50 + ks) * 2048) + (quad * 16 + (o & 15)) * 16;
    *(short8*)(base) = hs;
    *(short8*)(base + 1024) = ls;
}

// --- kscore: MFMA implicit GEMM -> per-(b,o,4row) partial stats -------------
// grid (2, 8, 16): x=mh (o-half 128), y=yb4 (4 rows), z=b. 256 thr = 4 waves.
// Wave wv owns row y0+wv (N=32px=2 tiles), all 8 M-tiles of the half.
__global__ __launch_bounds__(256, 1) void kscore(const float* __restrict__ A,
                                                 const char* __restrict__ Wpk,
                                                 float4* __restrict__ part) {
    __shared__ u16 slabh[8 * 36 * 68];   // [ry][xpad][68: 64g+4pad] 39168 B
    __shared__ u16 slabl[8 * 36 * 68];
    __shared__ float rawf[2112];         // 8g x 8ry x 33 transpose buffer
    int t = threadIdx.x;
    int mh = blockIdx.x, yb4 = blockIdx.y, b = blockIdx.z;
    int y0 = yb4 * 4;
    int lane = t & 63;
    int wv = __builtin_amdgcn_readfirstlane(t >> 6);
    int n15 = lane & 15, quad = lane >> 4;

    // zero border columns xpad in {0,1,34,35} (g 0..63) of both slabs
    {
        short4v z4 = {0, 0, 0, 0};
        for (int s = 0; s < 4; ++s) {
            int idx = s * 256 + t;               // 0..1023
            u16* sl = (idx >> 9) ? slabl : slabh;
            int rem = idx & 511;                 // 32 cells x 16 quads
            int cell = rem >> 4, q4 = rem & 15;
            int ry = cell >> 2, xpi = cell & 3;
            int xp = (xpi < 2) ? xpi : 32 + xpi;
            *(short4v*)(sl + (ry * 36 + xp) * 68 + q4 * 4) = z4;
        }
    }

    // stage A rows y0-2..y0+5, transposed to [ry][x][g], bf16 hi/lo
    for (int gc = 0; gc < 8; ++gc) {
        __syncthreads();
#pragma unroll
        for (int e = 0; e < 8; ++e) {
            int id = e * 256 + t;                // 0..2047
            int gl = id >> 8;
            int rem = id & 255;
            int ry = rem >> 5, x = rem & 31;
            int gy = y0 - 2 + ry;
            float v = 0.f;
            if (gy >= 0 && gy < 32)
                v = A[((b * NFM + gc * 8 + gl) * 32 + gy) * 32 + x];
            rawf[(gl * 8 + ry) * 33 + x] = v;
        }
        __syncthreads();
        {
            int ry = t >> 5, x = t & 31;
            short4v h0, h1, l0, l1;
#pragma unroll
            for (int j = 0; j < 8; ++j) {
                float v = rawf[(j * 8 + ry) * 33 + x];
                u16 h = f2bfbits(v);
                u16 l = f2bfbits(v - bf2f(h));
                if (j < 4) { h0[j] = (short)h; l0[j] = (short)l; }
                else       { h1[j - 4] = (short)h; l1[j - 4] = (short)l; }
            }
            int idx = (ry * 36 + x + 2) * 68 + gc * 8;
            *(short4v*)(slabh + idx) = h0;
            *(short4v*)(slabh + idx + 4) = h1;
            *(short4v*)(slabl + idx) = l0;
            *(short4v*)(slabl + idx + 4) = l1;
        }
    }
    __syncthreads();

    f32x4 acc[8][2];
#pragma unroll
    for (int mt = 0; mt < 8; ++mt)
#pragma unroll
        for (int nt = 0; nt < 2; ++nt)
#pragma unroll
            for (int r = 0; r < 4; ++r) acc[mt][nt][r] = 0.f;

    int bofs = n15 * 68 + quad * 8;   // lane part of B address (ushorts)
    const char* wrow = Wpk + (mh * 8) * 50 * 2048 + lane * 16;

    for (int ks = 0; ks < 50; ++ks) {
        int dydx = ks >> 1;
        int gh = (ks & 1) * 32;
        int dy = dydx / 5, dx = dydx - dy * 5;
        int rb = ((wv + dy) * 36 + dx) * 68 + gh + bofs;
        short8 bh0 = __builtin_shufflevector(*(const short4v*)(slabh + rb),
                                             *(const short4v*)(slabh + rb + 4),
                                             0, 1, 2, 3, 4, 5, 6, 7);
        short8 bl0 = __builtin_shufflevector(*(const short4v*)(slabl + rb),
                                             *(const short4v*)(slabl + rb + 4),
                                             0, 1, 2, 3, 4, 5, 6, 7);
        int rb1 = rb + 16 * 68;
        short8 bh1 = __builtin_shufflevector(*(const short4v*)(slabh + rb1),
                                             *(const short4v*)(slabh + rb1 + 4),
                                             0, 1, 2, 3, 4, 5, 6, 7);
        short8 bl1 = __builtin_shufflevector(*(const short4v*)(slabl + rb1),
                                             *(const short4v*)(slabl + rb1 + 4),
                                             0, 1, 2, 3, 4, 5, 6, 7);
#pragma unroll
        for (int mt = 0; mt < 8; ++mt) {
            const char* cb = wrow + (mt * 50 + ks) * 2048;
            short8 ah = *(const short8*)(cb);
            short8 al = *(const short8*)(cb + 1024);
            acc[mt][0] = __builtin_amdgcn_mfma_f32_16x16x32_bf16(ah, bh0, acc[mt][0], 0, 0, 0);
            acc[mt][1] = __builtin_amdgcn_mfma_f32_16x16x32_bf16(ah, bh1, acc[mt][1], 0, 0, 0);
            acc[mt][0] = __builtin_amdgcn_mfma_f32_16x16x32_bf16(ah, bl0, acc[mt][0], 0, 0, 0);
            acc[mt][1] = __builtin_amdgcn_mfma_f32_16x16x32_bf16(ah, bl1, acc[mt][1], 0, 0, 0);
            acc[mt][0] = __builtin_amdgcn_mfma_f32_16x16x32_bf16(al, bh0, acc[mt][0], 0, 0, 0);
            acc[mt][1] = __builtin_amdgcn_mfma_f32_16x16x32_bf16(al, bh1, acc[mt][1], 0, 0, 0);
        }
    }

    // per-wave stats: min/max/sum over this wave's 32 px, per o
#pragma unroll
    for (int mt = 0; mt < 8; ++mt)
#pragma unroll
        for (int r = 0; r < 4; ++r) {
            float v0 = acc[mt][0][r], v1 = acc[mt][1][r];
            float mn = fminf(v0, v1), mx = fmaxf(v0, v1), sm = v0 + v1;
#pragma unroll
            for (int msk = 1; msk <= 8; msk <<= 1) {
                mn = fminf(mn, __shfl_xor(mn, msk, 64));
                mx = fmaxf(mx, __shfl_xor(mx, msk, 64));
                sm += __shfl_xor(sm, msk, 64);
            }
            if (n15 == 0) {
                int ol = mt * 16 + quad * 4 + r;
                int ix = wv * 384 + ol * 3;
                rawf[ix] = mn; rawf[ix + 1] = mx; rawf[ix + 2] = sm;
            }
        }
    __syncthreads();
    if (t < 128) {
        float mn = 1e30f, mx = -1e30f, sm = 0.f;
#pragma unroll
        for (int w = 0; w < 4; ++w) {
            int ix = w * 384 + t * 3;
            mn = fminf(mn, rawf[ix]);
            mx = fmaxf(mx, rawf[ix + 1]);
            sm += rawf[ix + 2];
        }
        part[(b * NFC + mh * 128 + t) * 8 + yb4] = make_float4(mn, mx, sm, 0.f);
    }
}

// --- kfin: partials -> score -> argmax -> ig --------------------------------
__global__ __launch_bounds__(256) void kfin(const float4* __restrict__ part,
                                            const float* __restrict__ S,
                                            int* __restrict__ ig) {
    __shared__ float scl[NFC];
    int b = blockIdx.x, t = threadIdx.x;
    const float4* pp = part + (b * NFC + t) * 8;
    float mn = 1e30f, mx = -1e30f, sm = 0.f;
#pragma unroll
    for (int r = 0; r < 8; ++r) {
        float4 p = pp[r];
        mn = fminf(mn, p.x);
        mx = fmaxf(mx, p.y);
        sm += p.z;
    }
    float s = S[t] * (1.f / 64.f);
    float mnv = (s >= 0.f ? mn : mx) * s;
    float mxv = (s >= 0.f ? mx : mn) * s;
    float smv = sm * s;
    float d = mxv - mnv;
    scl[t] = d > 0.f ? (smv - 1024.f * mnv) / d : 0.f;
    __syncthreads();
    if (t < NFM) {
        float best = scl[t];
        int bi = 0;
#pragma unroll
        for (int n = 1; n < NMX; ++n) {
            float v = scl[n * NFM + t];
            if (v > best) { best = v; bi = n; }   // first-max ties
        }
        ig[b * NFM + t] = bi * NFM + t;
    }
}

// --- kout: gathered conv, fp32 VALU, bf16 weights. grid (16,2,16) -----------
__global__ __launch_bounds__(256) void kout(const float* __restrict__ A,
                                            const u16* __restrict__ w1h,
                                            const int* __restrict__ ig,
                                            float* __restrict__ out) {
    __shared__ __align__(16) float pa[4][20 * 36 + 4];
    __shared__ int igL[NFM];
    int t = threadIdx.x, z = blockIdx.y, b = blockIdx.z;
    if (t < NFM) igL[t] = ig[b * NFM + t];
    __syncthreads();   // igL ready; no more block barriers after this

    int wv = __builtin_amdgcn_readfirstlane(t >> 6);
    int lane = t & 63;
    int f = blockIdx.x * 4 + wv;
    int o = __builtin_amdgcn_readfirstlane(igL[f]);
    int y0 = z * 16;
    int xb = (lane & 7) * 4;
    int yb = (lane >> 3) * 2;
    float* buf = pa[wv];

    for (int i = lane; i < 20 * 36; i += 64) buf[i] = 0.f;
    __builtin_amdgcn_wave_barrier();

    const float* Ab = A + b * NFM * HW;
    int s0 = lane, s1 = lane + 64, s2 = lane + 128;
    int r0 = s0 >> 3, r1 = s1 >> 3, r2 = s2 >> 3;
    int gy0 = y0 - 2 + r0, gy1 = y0 - 2 + r1, gy2 = y0 - 2 + r2;
    bool v0 = (gy0 >= 0) && (gy0 < 32);
    bool v1 = (gy1 >= 0) && (gy1 < 32);
    bool v2 = (lane < 32) && (gy2 >= 0) && (gy2 < 32);
    float* d0 = &buf[r0 * 36 + (s0 & 7) * 4 + 2];
    float* d1 = &buf[r1 * 36 + (s1 & 7) * 4 + 2];
    float* d2 = &buf[r2 * 36 + (s2 & 7) * 4 + 2];
    int c0 = (s0 & 7) * 4, c1 = (s1 & 7) * 4, c2 = (s2 & 7) * 4;

    {
        if (v0) { float4 q = *(const float4*)(Ab + gy0 * 32 + c0);
                  *(float2*)&d0[0] = make_float2(q.x, q.y);
                  *(float2*)&d0[2] = make_float2(q.z, q.w); }
        if (v1) { float4 q = *(const float4*)(Ab + gy1 * 32 + c1);
                  *(float2*)&d1[0] = make_float2(q.x, q.y);
                  *(float2*)&d1[2] = make_float2(q.z, q.w); }
        if (v2) { float4 q = *(const float4*)(Ab + gy2 * 32 + c2);
                  *(float2*)&d2[0] = make_float2(q.x, q.y);
                  *(float2*)&d2[2] = make_float2(q.z, q.w); }
    }
    __builtin_amdgcn_wave_barrier();

    float acc[8];
#pragma unroll
    for (int j = 0; j < 8; ++j) acc[j] = 0.f;

    float wn[KK];
    {
        int ig0 = __builtin_amdgcn_readfirstlane(igL[0]);
        const u16* wp = w1h + (ig0 * NFC + o) * KK;
#pragma unroll
        for (int k = 0; k < KK; ++k) wn[k] = bf2f(wp[k]);
    }

    for (int g = 0; g < NFM; ++g) {
        float4 q0, q1, q2;
        bool more = (g + 1) < NFM;
        if (more) {
            const float* Ag = Ab + (g + 1) * HW;
            if (v0) q0 = *(const float4*)(Ag + gy0 * 32 + c0);
            if (v1) q1 = *(const float4*)(Ag + gy1 * 32 + c1);
            if (v2) q2 = *(const float4*)(Ag + gy2 * 32 + c2);
        }

        float wc[KK];
#pragma unroll
        for (int k = 0; k < KK; ++k) wc[k] = wn[k];
        if (more) {
            int ign = __builtin_amdgcn_readfirstlane(igL[g + 1]);
            const u16* wp = w1h + (ign * NFC + o) * KK;
#pragma unroll
            for (int k = 0; k < KK; ++k) wn[k] = bf2f(wp[k]);
        }

#pragma unroll
        for (int r = 0; r < 6; ++r) {
            float4 a0 = *(const float4*)&buf[(yb + r) * 36 + xb];
            float4 a1 = *(const float4*)&buf[(yb + r) * 36 + xb + 4];
            float a[8] = {a0.x, a0.y, a0.z, a0.w, a1.x, a1.y, a1.z, a1.w};
#pragma unroll
            for (int py = 0; py < 2; ++py) {
                int u = r - py;
                if (u >= 0 && u < 5) {
#pragma unroll
                    for (int v = 0; v < 5; ++v) {
                        float wvv = wc[u * 5 + v];
#pragma unroll
                        for (int px = 0; px < 4; ++px)
                            acc[py * 4 + px] = fmaf(a[px + v], wvv, acc[py * 4 + px]);
                    }
                }
            }
        }
        __builtin_amdgcn_wave_barrier();
        if (more) {
            if (v0) { *(float2*)&d0[0] = make_float2(q0.x, q0.y);
                      *(float2*)&d0[2] = make_float2(q0.z, q0.w); }
            if (v1) { *(float2*)&d1[0] = make_float2(q1.x, q1.y);
                      *(float2*)&d1[2] = make_float2(q1.z, q1.w); }
            if (v2) { *(float2*)&d2[0] = make_float2(q2.x, q2.y);
                      *(float2*)&d2[2] = make_float2(q2.z, q2.w); }
        }
        __builtin_amdgcn_wave_barrier();
    }

    float* ob = out + (b * NFM + f) * HW;
#pragma unroll
    for (int py = 0; py < 2; ++py) {
        float4 q;
        q.x = acc[py * 4 + 0] * (1.f / 64.f);
        q.y = acc[py * 4 + 1] * (1.f / 64.f);
        q.z = acc[py * 4 + 2] * (1.f / 64.f);
        q.w = acc[py * 4 + 3] * (1.f / 64.f);
        *(float4*)&ob[(y0 + yb + py) * 32 + xb] = q;
    }
}

extern "C" void kernel_launch(void* const* d_in, const int* in_sizes, int n_in,
                              void* d_out, int out_size, void* d_ws, size_t ws_size,
                              hipStream_t stream) {
    const float* A = (const float*)d_in[0];   // (16,64,32,32) f32
    const float* K = (const float*)d_in[1];   // (256,256,5,5) f32
    const float* S = (const float*)d_in[2];   // (256,) f32
    float* out = (float*)d_out;               // (16,64,32,32) f32

    char* ws = (char*)d_ws;
    char*   Wpk   = ws;                         // 1,638,400 B (packed MFMA weights)
    u16*    w1h   = (u16*)  (ws + 1638400);     // 3,276,800 B
    float*  wsum2 = (float*)(ws + 4915200);     // 1,638,400 B
    float4* part  = (float4*)(ws + 6553600);    //   524,288 B
    int*    igv   = (int*)  (ws + 7077888);     //     4,096 B  (end: 7,081,984)

    kprep<<<dim3(256), dim3(256), 0, stream>>>(K, w1h, wsum2);
    kpackW<<<dim3(200), dim3(256), 0, stream>>>(wsum2, Wpk);
    kscore<<<dim3(2, 8, 16), dim3(256), 0, stream>>>(A, Wpk, part);
    kfin<<<dim3(16), dim3(256), 0, stream>>>(part, S, igv);
    kout<<<dim3(16, 2, 16), dim3(256), 0, stream>>>(A, w1h, igv, out);
}

// Round 8
// 154.613 us; speedup vs baseline: 2.4463x; 1.3947x over previous
//
#include <hip/hip_runtime.h>

// LaterallyConnectedLayer: B=16, NUM_FM=64, N=4, NF=256, H=W=32, KS=5. fp32 I/O.
//   w1[i][o][k]   = minmax5x5( K[i][o] )
//   wsum[o][g][k] = sum_n w1[64n+g][o][k]
//   score[b,o]    = (sum-1024*min)/(max-min) over conv_same(A[b,:],wsum[o,:])*S[o]
//   n*[b,f]       = argmax_n score[b,64n+f]
//   out[b,f]      = (1/64) sum_g conv_same(A[b,g], w1[ig_g][ig_f]), ig_x = 64n*_x + x
// Both convs are implicit GEMMs on mfma_f32_16x16x32_bf16 with fp32 hi/lo split
// (hh+hl+lh). K-dim order: k_global = dydx*64 + g -> chunk ks = dydx*2+(g>=32),
// in-chunk k = quad*8+j with g = (ks&1)*32+quad*8+j. Fragment layouts per m89.

#define NFM 64
#define NMX 4
#define NFC 256
#define HW 1024
#define KK 25

typedef unsigned short u16;
typedef short short8 __attribute__((ext_vector_type(8)));
typedef float f32x4 __attribute__((ext_vector_type(4)));

__device__ __forceinline__ u16 f2bfbits(float f) {
    unsigned int u = __float_as_uint(f);
    u += 0x7fffu + ((u >> 16) & 1u);   // RNE
    return (u16)(u >> 16);
}
__device__ __forceinline__ float bf2f(u16 v) {
    return __uint_as_float(((unsigned int)v) << 16);
}

// --- kprep: wsum2[g][o][k] = sum_n minmax5x5(K[64n+g][o]) -------------------
// grid 256 = (g 0..63) x (o-quarter 0..3), 256 threads.
__global__ __launch_bounds__(256) void kprep(const float* __restrict__ K,
                                             float* __restrict__ wsum2) {
    __shared__ __align__(16) float buf[64 * KK];
    int g = blockIdx.x & 63, o0 = (blockIdx.x >> 6) * 64;
    int t = threadIdx.x;
    float wacc[KK];
#pragma unroll
    for (int k = 0; k < KK; ++k) wacc[k] = 0.f;

    for (int n = 0; n < NMX; ++n) {
        int i = n * NFM + g;
        const float4* src = (const float4*)(K + (i * NFC + o0) * KK);  // 400 f4
        __syncthreads();
        ((float4*)buf)[t] = src[t];
        if (t < 144) ((float4*)buf)[t + 256] = src[t + 256];
        __syncthreads();
        if (t < 64) {
            float v[KK];
            float mn = 1e30f, mx = -1e30f;
#pragma unroll
            for (int k = 0; k < KK; ++k) {
                v[k] = buf[t * KK + k];
                mn = fminf(mn, v[k]);
                mx = fmaxf(mx, v[k]);
            }
            float d = mx - mn;
            float r = d > 0.f ? 1.f / d : 0.f;
#pragma unroll
            for (int k = 0; k < KK; ++k) wacc[k] += (v[k] - mn) * r;
        }
    }
    __syncthreads();
    if (t < 64) {
#pragma unroll
        for (int k = 0; k < KK; ++k) buf[t * KK + k] = wacc[k];
    }
    __syncthreads();
    float4* dst = (float4*)(wsum2 + (g * NFC + o0) * KK);
    dst[t] = ((float4*)buf)[t];
    if (t < 144) dst[t + 256] = ((float4*)buf)[t + 256];
}

// --- kpackW: wsum2 -> Wpk, MFMA A-fragment order, hi/lo chunk pairs ---------
__global__ __launch_bounds__(256) void kpackW(const float* __restrict__ wsum2,
                                              char* __restrict__ Wpk) {
    int id = blockIdx.x * 256 + threadIdx.x;     // < 51200
    int o = id / 200;
    int rem = id - o * 200;
    int ks = rem >> 2, quad = rem & 3;
    int dydx = ks >> 1;
    int gb = (ks & 1) * 32 + quad * 8;
    short8 hs, ls;
#pragma unroll
    for (int j = 0; j < 8; ++j) {
        float v = wsum2[((gb + j) * NFC + o) * KK + dydx];
        u16 h = f2bfbits(v);
        float lo = v - bf2f(h);
        hs[j] = (short)h;
        ls[j] = (short)f2bfbits(lo);
    }
    char* base = Wpk + (((o >> 4) * 50 + ks) * 2048) + (quad * 16 + (o & 15)) * 16;
    *(short8*)(base) = hs;
    *(short8*)(base + 1024) = ls;
}

// --- kscore: grid (2 mh, 16 yb2, 16 b), 256 thr, 2 blocks/CU ----------------
// Wave = 2 M-tiles (32 o) x 4 npos (2 rows x 2 ntiles); weights read once per
// block; shared B-frags from LDS slab [ry][xi][g] (g-stride pad 72 -> b128).
__global__ __launch_bounds__(256, 2) void kscore(const float* __restrict__ A,
                                                 const char* __restrict__ Wpk,
                                                 float4* __restrict__ part) {
    __shared__ u16 slabh[6 * 36 * 72];   // 31104 B
    __shared__ u16 slabl[6 * 36 * 72];
    int t = threadIdx.x;
    int mh = blockIdx.x, yb2 = blockIdx.y, b = blockIdx.z;
    int y0 = yb2 * 2;
    int lane = t & 63;
    int wv = __builtin_amdgcn_readfirstlane(t >> 6);
    int n15 = lane & 15, quad = lane >> 4;

    const float* Ab = A + b * NFM * HW;
    for (int ry = 0; ry < 6; ++ry) {
        int gy = y0 - 2 + ry;
        bool rowok = (gy >= 0) && (gy < 32);
        for (int c = 0; c < 9; ++c) {
            int id2 = c * 256 + t;               // g*36 + xi
            int g = (id2 * 3641) >> 17;          // exact /36 for id2<2304
            int xi = id2 - g * 36;
            float v = 0.f;
            if (rowok && xi >= 2 && xi < 34)
                v = Ab[g * HW + gy * 32 + xi - 2];
            u16 h = f2bfbits(v);
            u16 l = f2bfbits(v - bf2f(h));
            int idx = (ry * 36 + xi) * 72 + g;
            slabh[idx] = h;
            slabl[idx] = l;
        }
    }
    __syncthreads();

    f32x4 acc[2][4];
#pragma unroll
    for (int m = 0; m < 2; ++m)
#pragma unroll
        for (int p = 0; p < 4; ++p)
#pragma unroll
            for (int r = 0; r < 4; ++r) acc[m][p][r] = 0.f;

    const char* wbase = Wpk + ((mh * 8 + wv * 2) * 50) * 2048 + lane * 16;

    for (int ks = 0; ks < 50; ++ks) {
        int dydx = ks >> 1;
        int gh = (ks & 1) * 32;
        int dy = dydx / 5, dx = dydx - dy * 5;
        short8 bh[4], bl[4];
#pragma unroll
        for (int p = 0; p < 4; ++p) {
            int r = p >> 1, nt = p & 1;
            int addr = ((r + dy) * 36 + nt * 16 + n15 + dx) * 72 + gh + quad * 8;
            bh[p] = *(const short8*)(slabh + addr);
            bl[p] = *(const short8*)(slabl + addr);
        }
#pragma unroll
        for (int m = 0; m < 2; ++m) {
            const char* cb = wbase + ((m * 50 + ks) << 11);
            short8 ah = *(const short8*)(cb);
            short8 al = *(const short8*)(cb + 1024);
#pragma unroll
            for (int p = 0; p < 4; ++p) {
                acc[m][p] = __builtin_amdgcn_mfma_f32_16x16x32_bf16(ah, bh[p], acc[m][p], 0, 0, 0);
                acc[m][p] = __builtin_amdgcn_mfma_f32_16x16x32_bf16(ah, bl[p], acc[m][p], 0, 0, 0);
                acc[m][p] = __builtin_amdgcn_mfma_f32_16x16x32_bf16(al, bh[p], acc[m][p], 0, 0, 0);
            }
        }
    }

#pragma unroll
    for (int m = 0; m < 2; ++m) {
#pragma unroll
        for (int reg = 0; reg < 4; ++reg) {
            float v0 = acc[m][0][reg], v1 = acc[m][1][reg];
            float v2 = acc[m][2][reg], v3 = acc[m][3][reg];
            float mn = fminf(fminf(v0, v1), fminf(v2, v3));
            float mx = fmaxf(fmaxf(v0, v1), fmaxf(v2, v3));
            float sm = (v0 + v1) + (v2 + v3);
#pragma unroll
            for (int msk = 1; msk <= 8; msk <<= 1) {
                mn = fminf(mn, __shfl_xor(mn, msk, 64));
                mx = fmaxf(mx, __shfl_xor(mx, msk, 64));
                sm += __shfl_xor(sm, msk, 64);
            }
            if (n15 == 0) {
                int o = mh * 128 + (wv * 2 + m) * 16 + quad * 4 + reg;
                part[(b * NFC + o) * 16 + yb2] = make_float4(mn, mx, sm, 0.f);
            }
        }
    }
}

// --- kfin: 16 partials -> score -> argmax -> ig[b*64+f] ---------------------
__global__ __launch_bounds__(256) void kfin(const float4* __restrict__ part,
                                            const float* __restrict__ S,
                                            int* __restrict__ ig) {
    __shared__ float scl[NFC];
    int b = blockIdx.x, t = threadIdx.x;
    const float4* pp = part + (b * NFC + t) * 16;
    float mn = 1e30f, mx = -1e30f, sm = 0.f;
#pragma unroll
    for (int r = 0; r < 16; ++r) {
        float4 p = pp[r];
        mn = fminf(mn, p.x);
        mx = fmaxf(mx, p.y);
        sm += p.z;
    }
    float s = S[t] * (1.f / 64.f);
    float mnv = (s >= 0.f ? mn : mx) * s;
    float mxv = (s >= 0.f ? mx : mn) * s;
    float smv = sm * s;
    float d = mxv - mnv;
    scl[t] = d > 0.f ? (smv - 1024.f * mnv) / d : 0.f;
    __syncthreads();
    if (t < NFM) {
        float best = scl[t];
        int bi = 0;
#pragma unroll
        for (int n = 1; n < NMX; ++n) {
            float v = scl[n * NFM + t];
            if (v > best) { best = v; bi = n; }   // first-max ties
        }
        ig[b * NFM + t] = bi * NFM + t;
    }
}

// --- kpackO: per-batch gathered weights, normalized from K, frag layout -----
// grid 256 = (b, f-quad); thread = (fl 0..3, g 0..63).
__global__ __launch_bounds__(256) void kpackO(const float* __restrict__ K,
                                              const int* __restrict__ ig,
                                              char* __restrict__ Wob) {
    __shared__ int igL[NFM];
    int b = blockIdx.x >> 4, fq = blockIdx.x & 15;
    int t = threadIdx.x;
    if (t < NFM) igL[t] = ig[b * NFM + t];
    __syncthreads();
    int fl = t >> 6, g = t & 63;
    int f = fq * 4 + fl;
    int o = igL[f], i = igL[g];
    const float* src = K + (i * NFC + o) * KK;
    float v[KK];
    float mn = 1e30f, mx = -1e30f;
#pragma unroll
    for (int k = 0; k < KK; ++k) {
        v[k] = src[k];
        mn = fminf(mn, v[k]);
        mx = fmaxf(mx, v[k]);
    }
    float d = mx - mn;
    float r = d > 0.f ? 1.f / d : 0.f;
    int gh = g >> 5;
    char* base = Wob + b * 409600 + (f >> 4) * 50 * 2048
               + ((((g & 31) >> 3) * 16 + (f & 15)) * 16) + (g & 7) * 2;
#pragma unroll
    for (int k = 0; k < KK; ++k) {
        float nv = (v[k] - mn) * r;
        u16 h = f2bfbits(nv);
        u16 l = f2bfbits(nv - bf2f(h));
        char* p = base + (2 * k + gh) * 2048;
        *(u16*)p = h;
        *(u16*)(p + 1024) = l;
    }
}

// --- kout: MFMA gathered conv. grid (2 xh, 16 yb2, 16 b), 4 blocks/CU-ish ---
// Wave = 1 M-tile (16 f) x 2 rows x 16 px.
__global__ __launch_bounds__(256, 2) void kout(const float* __restrict__ A,
                                               const char* __restrict__ Wob,
                                               float* __restrict__ out) {
    __shared__ u16 slabh[6 * 20 * 72];   // 17280 B
    __shared__ u16 slabl[6 * 20 * 72];
    int t = threadIdx.x;
    int xh = blockIdx.x, yb2 = blockIdx.y, b = blockIdx.z;
    int y0 = yb2 * 2, x0 = xh * 16;
    int lane = t & 63;
    int wv = __builtin_amdgcn_readfirstlane(t >> 6);
    int n15 = lane & 15, quad = lane >> 4;

    const float* Ab = A + b * NFM * HW;
    for (int ry = 0; ry < 6; ++ry) {
        int gy = y0 - 2 + ry;
        bool rowok = (gy >= 0) && (gy < 32);
        for (int c = 0; c < 5; ++c) {
            int id2 = c * 256 + t;               // g*20 + xi
            int g = (id2 * 6554) >> 17;          // exact /20 for id2<1280
            int xi = id2 - g * 20;
            int x = x0 + xi - 2;
            float v = 0.f;
            if (rowok && x >= 0 && x < 32)
                v = Ab[g * HW + gy * 32 + x];
            u16 h = f2bfbits(v);
            u16 l = f2bfbits(v - bf2f(h));
            int idx = (ry * 20 + xi) * 72 + g;
            slabh[idx] = h;
            slabl[idx] = l;
        }
    }
    __syncthreads();

    f32x4 acc[2];
#pragma unroll
    for (int r = 0; r < 2; ++r)
#pragma unroll
        for (int j = 0; j < 4; ++j) acc[r][j] = 0.f;

    const char* wbase = Wob + b * 409600 + (wv * 50) * 2048 + lane * 16;

    for (int ks = 0; ks < 50; ++ks) {
        int dydx = ks >> 1;
        int gh = (ks & 1) * 32;
        int dy = dydx / 5, dx = dydx - dy * 5;
        const char* cb = wbase + (ks << 11);
        short8 ah = *(const short8*)(cb);
        short8 al = *(const short8*)(cb + 1024);
#pragma unroll
        for (int r = 0; r < 2; ++r) {
            int addr = ((r + dy) * 20 + n15 + dx) * 72 + gh + quad * 8;
            short8 bh = *(const short8*)(slabh + addr);
            short8 bl = *(const short8*)(slabl + addr);
            acc[r] = __builtin_amdgcn_mfma_f32_16x16x32_bf16(ah, bh, acc[r], 0, 0, 0);
            acc[r] = __builtin_amdgcn_mfma_f32_16x16x32_bf16(ah, bl, acc[r], 0, 0, 0);
            acc[r] = __builtin_amdgcn_mfma_f32_16x16x32_bf16(al, bh, acc[r], 0, 0, 0);
        }
    }

#pragma unroll
    for (int r = 0; r < 2; ++r)
#pragma unroll
        for (int reg = 0; reg < 4; ++reg) {
            int f = wv * 16 + quad * 4 + reg;
            out[(b * NFM + f) * HW + (y0 + r) * 32 + x0 + n15] = acc[r][reg] * (1.f / 64.f);
        }
}

extern "C" void kernel_launch(void* const* d_in, const int* in_sizes, int n_in,
                              void* d_out, int out_size, void* d_ws, size_t ws_size,
                              hipStream_t stream) {
    const float* A = (const float*)d_in[0];   // (16,64,32,32) f32
    const float* K = (const float*)d_in[1];   // (256,256,5,5) f32
    const float* S = (const float*)d_in[2];   // (256,) f32
    float* out = (float*)d_out;               // (16,64,32,32) f32

    char* ws = (char*)d_ws;
    char*   Wpk   = ws;                         // [0, 1,638,400)
    float*  wsum2 = (float*)(ws + 1638400);     // [1.64M, 3.28M)  dead after kpackW
    float4* part  = (float4*)(ws + 3276800);    // [3.28M, 4.33M)  dead after kfin
    char*   Wob   = ws + 1638400;               // [1.64M, 8.19M)  written by kpackO
    int*    igv   = (int*)(ws + 8192000);       // [8.19M, +4KB)

    kprep<<<dim3(256), dim3(256), 0, stream>>>(K, wsum2);
    kpackW<<<dim3(200), dim3(256), 0, stream>>>(wsum2, Wpk);
    kscore<<<dim3(2, 16, 16), dim3(256), 0, stream>>>(A, Wpk, part);
    kfin<<<dim3(16), dim3(256), 0, stream>>>(part, S, igv);
    kpackO<<<dim3(256), dim3(256), 0, stream>>>(K, igv, Wob);
    kout<<<dim3(2, 16, 16), dim3(256), 0, stream>>>(A, Wob, out);
}